// Round 1
// baseline (1742.022 us; speedup 1.0000x reference)
//
#include <hip/hip_runtime.h>
#include <hip/hip_bf16.h>
#include <stdint.h>

// Problem constants (static ragged structure)
#define M_TOTAL 16384
#define GK 2048   // HIDDEN
#define GN 8192   // FFN

typedef __attribute__((ext_vector_type(4))) float floatx4;
typedef __attribute__((ext_vector_type(8))) __bf16 bf16x8;

#define AS_GLOBAL(p) ((__attribute__((address_space(1))) void*)(p))
#define AS_LDS(p)    ((__attribute__((address_space(3))) void*)(p))

__device__ __forceinline__ unsigned short f2bf(float f) {
    unsigned int u = __float_as_uint(f);
    unsigned int r = (u + 0x7fffu + ((u >> 16) & 1u)) >> 16;   // RNE
    return (unsigned short)r;
}

// ---------------------------------------------------------------------------
// Kernel 1: hidden_states fp32 -> bf16 (flat, float4 -> ushort4)
// ---------------------------------------------------------------------------
__global__ __launch_bounds__(256) void cvt_hs(const float4* __restrict__ X,
                                              ushort4* __restrict__ Y) {
    size_t i = (size_t)blockIdx.x * 256 + threadIdx.x;
    float4 v = X[i];
    Y[i] = make_ushort4(f2bf(v.x), f2bf(v.y), f2bf(v.z), f2bf(v.w));
}

// ---------------------------------------------------------------------------
// Kernel 2: weights [g][K][N] fp32 -> Wt [g][N][K] bf16, 64x64 LDS tiles
// grid: (GN/64, GK/64, 8), block 256
// ---------------------------------------------------------------------------
__global__ __launch_bounds__(256) void transpose_w(const float* __restrict__ W,
                                                   unsigned short* __restrict__ Wt) {
    __shared__ float ls[64][65];
    const int g  = blockIdx.z;
    const int n0 = blockIdx.x * 64;
    const int k0 = blockIdx.y * 64;
    const float* Wg = W + (size_t)g * GK * GN;
    unsigned short* Wtg = Wt + (size_t)g * GN * GK;

    const int t  = threadIdx.x;
    const int c4 = (t & 15) * 4;   // 0..60 step 4
    const int rb = t >> 4;         // 0..15

    #pragma unroll
    for (int i = 0; i < 4; ++i) {
        int r = i * 16 + rb;       // k-local
        float4 v = *(const float4*)(Wg + (size_t)(k0 + r) * GN + n0 + c4);
        ls[r][c4 + 0] = v.x; ls[r][c4 + 1] = v.y;
        ls[r][c4 + 2] = v.z; ls[r][c4 + 3] = v.w;
    }
    __syncthreads();
    #pragma unroll
    for (int i = 0; i < 4; ++i) {
        int n = i * 16 + rb;       // n-local
        ushort4 o = make_ushort4(f2bf(ls[c4 + 0][n]), f2bf(ls[c4 + 1][n]),
                                 f2bf(ls[c4 + 2][n]), f2bf(ls[c4 + 3][n]));
        *(ushort4*)(Wtg + (size_t)(n0 + n) * GK + k0 + c4) = o;
    }
}

// ---------------------------------------------------------------------------
// Kernel 3: grouped GEMM, m97 structure.
// A  : [16384][2048] bf16 (K contiguous)
// Bt : [8][8192][2048] bf16 (K contiguous per FFN column)
// C  : [16384][8192] fp32
// Block 256 (4 waves, 2x2), tile 128x128, BK=32.
// grid: (GN/128=64, M_TOTAL/128=128)
// ---------------------------------------------------------------------------
__global__ __launch_bounds__(256) void gemm_kernel(const unsigned short* __restrict__ A,
                                                   const unsigned short* __restrict__ Bt,
                                                   float* __restrict__ C) {
    __shared__ __align__(16) unsigned short As[128 * 32];
    __shared__ __align__(16) unsigned short Bs[128 * 32];

    const int t    = threadIdx.x;
    const int wave = t >> 6;
    const int lane = t & 63;
    const int n0   = blockIdx.x * 128;
    const int m0   = blockIdx.y * 128;

    // group lookup (all boundaries multiples of 128, so a tile never straddles)
    const int g = (m0 >= 14336) ? 7 : (m0 >= 11264) ? 6 : (m0 >= 9216) ? 5 :
                  (m0 >= 6656)  ? 4 : (m0 >= 4608)  ? 3 : (m0 >= 2560) ? 2 :
                  (m0 >= 1024)  ? 1 : 0;
    const unsigned short* Bg = Bt + (size_t)g * GN * GK;

    // staging pointers: chunk id = c*256 + t covers tile bytes [chunk*16, +16)
    // row = chunk/4, k-elem offset = (chunk%4)*8
    const unsigned short* ga0 = A  + (size_t)(m0 + (t >> 2)) * GK + (t & 3) * 8;
    const unsigned short* ga1 = ga0 + (size_t)64 * GK;
    const unsigned short* gb0 = Bg + (size_t)(n0 + (t >> 2)) * GK + (t & 3) * 8;
    const unsigned short* gb1 = gb0 + (size_t)64 * GK;

    // wave-uniform LDS bases (HW scatters lane i at base + i*16)
    char* aL = (char*)As + wave * 1024;
    char* bL = (char*)Bs + wave * 1024;

    floatx4 acc[4][4];
    #pragma unroll
    for (int i = 0; i < 4; ++i)
        #pragma unroll
        for (int j = 0; j < 4; ++j)
            acc[i][j] = (floatx4){0.f, 0.f, 0.f, 0.f};

    const int wm = (wave >> 1) * 64;
    const int wn = (wave & 1) * 64;
    const int fr = lane & 15;          // fragment row (m for A, n for B)
    const int kb = (lane >> 4) * 8;    // k sub-offset

    for (int k0 = 0; k0 < GK; k0 += 32) {
        __builtin_amdgcn_global_load_lds(AS_GLOBAL(ga0), AS_LDS(aL),        16, 0, 0);
        __builtin_amdgcn_global_load_lds(AS_GLOBAL(ga1), AS_LDS(aL + 4096), 16, 0, 0);
        __builtin_amdgcn_global_load_lds(AS_GLOBAL(gb0), AS_LDS(bL),        16, 0, 0);
        __builtin_amdgcn_global_load_lds(AS_GLOBAL(gb1), AS_LDS(bL + 4096), 16, 0, 0);
        ga0 += 32; ga1 += 32; gb0 += 32; gb1 += 32;
        __syncthreads();

        bf16x8 af[4], bfv[4];
        #pragma unroll
        for (int i = 0; i < 4; ++i) {
            af[i]  = *(const bf16x8*)(As + (wm + i * 16 + fr) * 32 + kb);
            bfv[i] = *(const bf16x8*)(Bs + (wn + i * 16 + fr) * 32 + kb);
        }
        #pragma unroll
        for (int i = 0; i < 4; ++i)
            #pragma unroll
            for (int j = 0; j < 4; ++j)
                acc[i][j] = __builtin_amdgcn_mfma_f32_16x16x32_bf16(af[i], bfv[j], acc[i][j], 0, 0, 0);
        __syncthreads();
    }

    // Epilogue: C/D layout col = lane&15, row = (lane>>4)*4 + reg
    const int orow = m0 + wm + (lane >> 4) * 4;
    const int ocol = n0 + wn + (lane & 15);
    #pragma unroll
    for (int i = 0; i < 4; ++i)
        #pragma unroll
        for (int j = 0; j < 4; ++j)
            #pragma unroll
            for (int r = 0; r < 4; ++r)
                C[(size_t)(orow + i * 16 + r) * GN + ocol + j * 16] = acc[i][j][r];
}

// ---------------------------------------------------------------------------
extern "C" void kernel_launch(void* const* d_in, const int* in_sizes, int n_in,
                              void* d_out, int out_size, void* d_ws, size_t ws_size,
                              hipStream_t stream) {
    const float* hs = (const float*)d_in[0];   // [16384][2048] fp32
    const float* w  = (const float*)d_in[1];   // [8][2048][8192] fp32
    float* out = (float*)d_out;                // [16384][8192] fp32

    unsigned short* hsb = (unsigned short*)d_ws;                    // 16384*2048 bf16
    unsigned short* wtb = hsb + (size_t)M_TOTAL * GK;               // 8*8192*2048 bf16

    // 1) hidden fp32 -> bf16 : 33,554,432 elems / 4 per thread / 256 per block
    cvt_hs<<<(M_TOTAL * GK) / (4 * 256), 256, 0, stream>>>((const float4*)hs, (ushort4*)hsb);

    // 2) weights fp32 [g][K][N] -> bf16 [g][N][K]
    transpose_w<<<dim3(GN / 64, GK / 64, 8), 256, 0, stream>>>(w, wtb);

    // 3) grouped GEMM
    gemm_kernel<<<dim3(GN / 128, M_TOTAL / 128), 256, 0, stream>>>(hsb, wtb, out);
}